// Round 1
// baseline (351.750 us; speedup 1.0000x reference)
//
#include <hip/hip_runtime.h>

#define Bn 16384
#define Hn 128
#define Gn 5
#define Tn 12

typedef __attribute__((ext_vector_type(8))) __bf16 bf16x8;
typedef __attribute__((ext_vector_type(4))) float f32x4;
typedef unsigned int u32;
typedef unsigned short u16;

#define MFMA(a, b, c) __builtin_amdgcn_mfma_f32_16x16x32_bf16((a), (b), (c), 0, 0, 0)

__device__ __forceinline__ u16 f2bf(float f) { return __builtin_bit_cast(u16, (__bf16)f); }
__device__ __forceinline__ float bf2f(u16 h) { u32 u = ((u32)h) << 16; return __builtin_bit_cast(float, u); }
__device__ __forceinline__ float sigf(float x) {
    return __builtin_amdgcn_rcpf(1.0f + __builtin_amdgcn_exp2f(-1.44269504f * x));
}
__device__ __forceinline__ float tanhf_(float x) {
    return 1.0f - 2.0f * __builtin_amdgcn_rcpf(1.0f + __builtin_amdgcn_exp2f(2.88539008f * x));
}

// Swizzled byte offsets (chunk-XOR to kill bank conflicts on A-fragment reads).
// [rows][128] bf16 tile: 256 B rows, 16 chunks of 16 B
__device__ __forceinline__ int hbsw(int row, int bytein) {
    return row * 256 + ((((bytein >> 4) ^ row) & 15) << 4) + (bytein & 15);
}
// [rows][64] bf16 tile: 128 B rows, 8 chunks
__device__ __forceinline__ int pbsw(int row, int bytein) {
    return row * 128 + ((((bytein >> 4) ^ row) & 7) << 4) + (bytein & 15);
}
// [rows][32] bf16 tile: 64 B rows, 4 chunks
__device__ __forceinline__ int xbsw(int row, int bytein) {
    return row * 64 + ((((bytein >> 4) ^ row) & 3) << 4) + (bytein & 15);
}

// ---------------- Kernel 1: goals + goal_probs (phase A) ----------------
__global__ __launch_bounds__(256) void k_phaseA(
    const float* __restrict__ eh, const float* __restrict__ lastpos,
    const float* __restrict__ gp_w1, const float* __restrict__ gp_b1,
    const float* __restrict__ gp_w2, const float* __restrict__ gp_b2,
    const float* __restrict__ pr_w1, const float* __restrict__ pr_b1,
    const float* __restrict__ pr_w2, const float* __restrict__ pr_b2,
    float* __restrict__ goals_o, float* __restrict__ probs_o)
{
    __shared__ __align__(16) char eT[64 * 256];  // [64][128] bf16
    __shared__ __align__(16) char gT[64 * 256];  // [64][128] bf16
    __shared__ __align__(16) char pT[64 * 128];  // [64][64] bf16
    __shared__ float lgT[64 * 8];

    const int tid = threadIdx.x;
    const int lane = tid & 63;
    const int wv = tid >> 6;           // 0..3
    const int lg = lane >> 4, li = lane & 15;
    const int r0 = blockIdx.x * 64;
    const int rowbase = wv * 16;

    // stage eh -> bf16 LDS (swizzled)
    {
        int row = tid >> 2, seg = tid & 3;
        const float* src = eh + (size_t)(r0 + row) * Hn + seg * 32;
#pragma unroll
        for (int cc = 0; cc < 4; ++cc) {
            u32 p0 = (u32)f2bf(src[cc * 8 + 0]) | ((u32)f2bf(src[cc * 8 + 1]) << 16);
            u32 p1 = (u32)f2bf(src[cc * 8 + 2]) | ((u32)f2bf(src[cc * 8 + 3]) << 16);
            u32 p2 = (u32)f2bf(src[cc * 8 + 4]) | ((u32)f2bf(src[cc * 8 + 5]) << 16);
            u32 p3 = (u32)f2bf(src[cc * 8 + 6]) | ((u32)f2bf(src[cc * 8 + 7]) << 16);
            *(uint4*)(eT + hbsw(row, seg * 64 + cc * 16)) = make_uint4(p0, p1, p2, p3);
        }
    }
    __syncthreads();

    bf16x8 Ae[4];
#pragma unroll
    for (int kc = 0; kc < 4; ++kc)
        Ae[kc] = *(const bf16x8*)(eT + hbsw(rowbase + li, kc * 64 + lg * 16));

    // g_hid = relu(eh @ gp_w1 + gp_b1)
#pragma unroll 1
    for (int nt = 0; nt < 8; ++nt) {
        int c1 = nt * 16 + li;
        f32x4 acc = {0.f, 0.f, 0.f, 0.f};
#pragma unroll
        for (int kc = 0; kc < 4; ++kc) {
            bf16x8 bfr;
#pragma unroll
            for (int j = 0; j < 8; ++j)
                bfr[j] = (__bf16)gp_w1[(size_t)(kc * 32 + lg * 8 + j) * Hn + c1];
            acc = MFMA(Ae[kc], bfr, acc);
        }
        float bias = gp_b1[c1];
#pragma unroll
        for (int r = 0; r < 4; ++r) {
            int row = rowbase + lg * 4 + r;
            float v = fmaxf(acc[r] + bias, 0.f);
            *(u16*)(gT + hbsw(row, c1 * 2)) = f2bf(v);
        }
    }
    __syncthreads();

    // goals = g_hid @ gp_w2 + gp_b2 + last_pos
    {
        bf16x8 Ag[4];
#pragma unroll
        for (int kc = 0; kc < 4; ++kc)
            Ag[kc] = *(const bf16x8*)(gT + hbsw(rowbase + li, kc * 64 + lg * 16));
        f32x4 acc = {0.f, 0.f, 0.f, 0.f};
#pragma unroll
        for (int kc = 0; kc < 4; ++kc) {
            bf16x8 bfr;
#pragma unroll
            for (int j = 0; j < 8; ++j) {
                int k = kc * 32 + lg * 8 + j;
                bfr[j] = (li < 10) ? (__bf16)gp_w2[k * 10 + li] : (__bf16)0.f;
            }
            acc = MFMA(Ag[kc], bfr, acc);
        }
        if (li < 10) {
            float b2 = gp_b2[li];
#pragma unroll
            for (int r = 0; r < 4; ++r) {
                int b = r0 + rowbase + lg * 4 + r;
                float v = acc[r] + b2 + lastpos[(size_t)b * 2 + (li & 1)];
                goals_o[(size_t)b * 10 + li] = v;
            }
        }
    }

    // p_hid = relu(eh @ pr_w1 + pr_b1)
#pragma unroll 1
    for (int nt = 0; nt < 4; ++nt) {
        int c1 = nt * 16 + li;
        f32x4 acc = {0.f, 0.f, 0.f, 0.f};
#pragma unroll
        for (int kc = 0; kc < 4; ++kc) {
            bf16x8 bfr;
#pragma unroll
            for (int j = 0; j < 8; ++j)
                bfr[j] = (__bf16)pr_w1[(size_t)(kc * 32 + lg * 8 + j) * 64 + c1];
            acc = MFMA(Ae[kc], bfr, acc);
        }
        float bias = pr_b1[c1];
#pragma unroll
        for (int r = 0; r < 4; ++r) {
            int row = rowbase + lg * 4 + r;
            float v = fmaxf(acc[r] + bias, 0.f);
            *(u16*)(pT + pbsw(row, c1 * 2)) = f2bf(v);
        }
    }
    __syncthreads();

    // logits = p_hid @ pr_w2 + pr_b2
    {
        bf16x8 Ap[2];
#pragma unroll
        for (int kc = 0; kc < 2; ++kc)
            Ap[kc] = *(const bf16x8*)(pT + pbsw(rowbase + li, kc * 64 + lg * 16));
        f32x4 acc = {0.f, 0.f, 0.f, 0.f};
#pragma unroll
        for (int kc = 0; kc < 2; ++kc) {
            bf16x8 bfr;
#pragma unroll
            for (int j = 0; j < 8; ++j) {
                int k = kc * 32 + lg * 8 + j;
                bfr[j] = (li < 5) ? (__bf16)pr_w2[k * 5 + li] : (__bf16)0.f;
            }
            acc = MFMA(Ap[kc], bfr, acc);
        }
        if (li < 5) {
            float b2 = pr_b2[li];
#pragma unroll
            for (int r = 0; r < 4; ++r) {
                int row = rowbase + lg * 4 + r;
                lgT[row * 8 + li] = acc[r] + b2;
            }
        }
    }
    __syncthreads();

    if (tid < 64) {
        int row = tid;
        float v0 = lgT[row * 8 + 0], v1 = lgT[row * 8 + 1], v2 = lgT[row * 8 + 2];
        float v3 = lgT[row * 8 + 3], v4 = lgT[row * 8 + 4];
        float mx = fmaxf(fmaxf(fmaxf(v0, v1), fmaxf(v2, v3)), v4);
        float e0 = __builtin_amdgcn_exp2f((v0 - mx) * 1.44269504f);
        float e1 = __builtin_amdgcn_exp2f((v1 - mx) * 1.44269504f);
        float e2 = __builtin_amdgcn_exp2f((v2 - mx) * 1.44269504f);
        float e3 = __builtin_amdgcn_exp2f((v3 - mx) * 1.44269504f);
        float e4 = __builtin_amdgcn_exp2f((v4 - mx) * 1.44269504f);
        float rs = __builtin_amdgcn_rcpf(e0 + e1 + e2 + e3 + e4);
        size_t ob = (size_t)(r0 + row) * 5;
        probs_o[ob + 0] = e0 * rs;
        probs_o[ob + 1] = e1 * rs;
        probs_o[ob + 2] = e2 * rs;
        probs_o[ob + 3] = e3 * rs;
        probs_o[ob + 4] = e4 * rs;
    }
}

// ---------------- Kernel 2: LSTM rollout ----------------
// 64 rows (b*G+g major) per workgroup, 512 threads (8 waves).
// Wave w owns hidden columns [w*16, w*16+16) at all 4 gate offsets.
__global__ __launch_bounds__(512) void k_lstm(
    const float* __restrict__ eh, const float* __restrict__ ec,
    const float* __restrict__ lastpos,
    const float* __restrict__ w_ih, const float* __restrict__ w_hh,
    const float* __restrict__ b_ih, const float* __restrict__ b_hh,
    const float* __restrict__ ph_w, const float* __restrict__ ph_b,
    const float* __restrict__ goals_o, float* __restrict__ preds)
{
    __shared__ __align__(16) char hT[64 * 256];  // [64][128] bf16, swizzled
    __shared__ __align__(16) char xT[64 * 64];   // [64][32] bf16, swizzled
    __shared__ float pos2[64 * 2];
    __shared__ float phwl[256];
    __shared__ float phbl[2];

    const int tid = threadIdx.x;
    const int lane = tid & 63;
    const int wv = tid >> 6;            // 0..7
    const int lg = lane >> 4, li = lane & 15;
    const int col = wv * 16 + li;       // hidden column 0..127
    const int r0 = blockIdx.x * 64;

    // --- w_hh / w_ih+bias B-fragments in registers (live across all T steps)
    bf16x8 Bh[4][4];
    bf16x8 Bx[4];
#pragma unroll
    for (int gt = 0; gt < 4; ++gt) {
        const int cg = gt * 128 + col;
#pragma unroll
        for (int kc = 0; kc < 4; ++kc) {
            bf16x8 f;
#pragma unroll
            for (int j = 0; j < 8; ++j)
                f[j] = (__bf16)w_hh[(size_t)(kc * 32 + lg * 8 + j) * 512 + cg];
            Bh[gt][kc] = f;
        }
        bf16x8 fx;
#pragma unroll
        for (int j = 0; j < 8; ++j) {
            int k = lg * 8 + j;
            float v = 0.f;
            if (k < 4) v = w_ih[k * 512 + cg];
            else if (k == 4) v = b_ih[cg] + b_hh[cg];
            fx[j] = (__bf16)v;
        }
        Bx[gt] = fx;
    }

    // --- stage h0 = encoder_hidden (broadcast over g)
    {
        int row = tid >> 3, seg = tid & 7;
        int b = (r0 + row) / 5;
        const float* src = eh + (size_t)b * Hn + seg * 16;
#pragma unroll
        for (int cp = 0; cp < 2; ++cp) {
            u32 p0 = (u32)f2bf(src[cp * 8 + 0]) | ((u32)f2bf(src[cp * 8 + 1]) << 16);
            u32 p1 = (u32)f2bf(src[cp * 8 + 2]) | ((u32)f2bf(src[cp * 8 + 3]) << 16);
            u32 p2 = (u32)f2bf(src[cp * 8 + 4]) | ((u32)f2bf(src[cp * 8 + 5]) << 16);
            u32 p3 = (u32)f2bf(src[cp * 8 + 6]) | ((u32)f2bf(src[cp * 8 + 7]) << 16);
            *(uint4*)(hT + hbsw(row, seg * 32 + cp * 16)) = make_uint4(p0, p1, p2, p3);
        }
    }
    // --- stage x0 = [pos, goal, 1, 0...] and pos master copy
    if (tid < 64) {
        int row = tid, gr = r0 + row, b = gr / 5;
        float px = lastpos[2 * b], py = lastpos[2 * b + 1];
        float gx = goals_o[2 * gr], gy = goals_o[2 * gr + 1];
        u32 c0 = (u32)f2bf(px) | ((u32)f2bf(py) << 16);
        u32 c1 = (u32)f2bf(gx) | ((u32)f2bf(gy) << 16);
        u32 c2 = (u32)f2bf(1.0f);
        *(uint4*)(xT + xbsw(row, 0)) = make_uint4(c0, c1, c2, 0u);
        *(uint4*)(xT + xbsw(row, 16)) = make_uint4(0u, 0u, 0u, 0u);
        *(uint4*)(xT + xbsw(row, 32)) = make_uint4(0u, 0u, 0u, 0u);
        *(uint4*)(xT + xbsw(row, 48)) = make_uint4(0u, 0u, 0u, 0u);
        pos2[2 * row] = px;
        pos2[2 * row + 1] = py;
    }
    if (tid < 256) phwl[tid] = ph_w[tid];
    if (tid == 511) { phbl[0] = ph_b[0]; phbl[1] = ph_b[1]; }

    // --- c0 in registers (f32 master)
    float c[4][4];
#pragma unroll
    for (int m = 0; m < 4; ++m)
#pragma unroll
        for (int r = 0; r < 4; ++r)
            c[m][r] = ec[(size_t)((r0 + m * 16 + lg * 4 + r) / 5) * Hn + col];

    __syncthreads();

#pragma unroll 1
    for (int t = 0; t < Tn; ++t) {
        u32 hn[4][2];
#pragma unroll
        for (int m = 0; m < 4; ++m) {
            f32x4 a0 = {0.f, 0.f, 0.f, 0.f}, a1 = {0.f, 0.f, 0.f, 0.f};
            f32x4 a2 = {0.f, 0.f, 0.f, 0.f}, a3 = {0.f, 0.f, 0.f, 0.f};
#pragma unroll
            for (int kc = 0; kc < 4; ++kc) {
                bf16x8 A = *(const bf16x8*)(hT + hbsw(m * 16 + li, kc * 64 + lg * 16));
                a0 = MFMA(A, Bh[0][kc], a0);
                a1 = MFMA(A, Bh[1][kc], a1);
                a2 = MFMA(A, Bh[2][kc], a2);
                a3 = MFMA(A, Bh[3][kc], a3);
            }
            {
                bf16x8 A = *(const bf16x8*)(xT + xbsw(m * 16 + li, lg * 16));
                a0 = MFMA(A, Bx[0], a0);
                a1 = MFMA(A, Bx[1], a1);
                a2 = MFMA(A, Bx[2], a2);
                a3 = MFMA(A, Bx[3], a3);
            }
#pragma unroll
            for (int r = 0; r < 4; ++r) {
                float iv = a0[r], fv = a1[r], gv = a2[r], ov = a3[r];
                float cn = sigf(fv) * c[m][r] + sigf(iv) * tanhf_(gv);
                c[m][r] = cn;
                float hv = sigf(ov) * tanhf_(cn);
                u32 hbits = (u32)f2bf(hv);
                if ((r & 1) == 0) hn[m][r >> 1] = hbits;
                else hn[m][r >> 1] |= hbits << 16;
            }
        }
        __syncthreads();   // everyone done reading old h
#pragma unroll
        for (int m = 0; m < 4; ++m) {
#pragma unroll
            for (int r = 0; r < 4; ++r) {
                int row = m * 16 + lg * 4 + r;
                u16 hv = (u16)(hn[m][r >> 1] >> (16 * (r & 1)));
                *(u16*)(hT + hbsw(row, col * 2)) = hv;
            }
        }
        __syncthreads();   // h_new visible
        // --- pos update: pos += h_new @ ph_w + ph_b, write prediction, refresh x
        {
            int row = tid >> 3, seg = tid & 7;
            float sx = 0.f, sy = 0.f;
#pragma unroll
            for (int cp = 0; cp < 2; ++cp) {
                uint4 d = *(const uint4*)(hT + hbsw(row, seg * 32 + cp * 16));
                u32 dws[4] = {d.x, d.y, d.z, d.w};
                int cb = seg * 16 + cp * 8;
#pragma unroll
                for (int j = 0; j < 4; ++j) {
                    float h0 = bf2f((u16)(dws[j] & 0xFFFFu));
                    float h1 = bf2f((u16)(dws[j] >> 16));
                    int cidx = cb + 2 * j;
                    sx += h0 * phwl[cidx * 2 + 0] + h1 * phwl[cidx * 2 + 2];
                    sy += h0 * phwl[cidx * 2 + 1] + h1 * phwl[cidx * 2 + 3];
                }
            }
            sx += __shfl_xor(sx, 1); sy += __shfl_xor(sy, 1);
            sx += __shfl_xor(sx, 2); sy += __shfl_xor(sy, 2);
            sx += __shfl_xor(sx, 4); sy += __shfl_xor(sy, 4);
            if (seg == 0) {
                float px = pos2[2 * row] + sx + phbl[0];
                float py = pos2[2 * row + 1] + sy + phbl[1];
                pos2[2 * row] = px;
                pos2[2 * row + 1] = py;
                size_t o = ((size_t)(r0 + row) * Tn + t) * 2;
                preds[o] = px;
                preds[o + 1] = py;
                *(u32*)(xT + xbsw(row, 0)) = (u32)f2bf(px) | ((u32)f2bf(py) << 16);
            }
        }
        __syncthreads();   // x ready for next step
    }
}

extern "C" void kernel_launch(void* const* d_in, const int* in_sizes, int n_in,
                              void* d_out, int out_size, void* d_ws, size_t ws_size,
                              hipStream_t stream)
{
    (void)in_sizes; (void)n_in; (void)out_size; (void)d_ws; (void)ws_size;
    const float* eh   = (const float*)d_in[0];
    const float* ec   = (const float*)d_in[1];
    const float* lp   = (const float*)d_in[2];
    const float* gpw1 = (const float*)d_in[3];
    const float* gpb1 = (const float*)d_in[4];
    const float* gpw2 = (const float*)d_in[5];
    const float* gpb2 = (const float*)d_in[6];
    const float* prw1 = (const float*)d_in[7];
    const float* prb1 = (const float*)d_in[8];
    const float* prw2 = (const float*)d_in[9];
    const float* prb2 = (const float*)d_in[10];
    const float* wih  = (const float*)d_in[11];
    const float* whh  = (const float*)d_in[12];
    const float* bih  = (const float*)d_in[13];
    const float* bhh  = (const float*)d_in[14];
    const float* phw  = (const float*)d_in[15];
    const float* phb  = (const float*)d_in[16];

    float* out = (float*)d_out;
    float* preds = out;                                            // [B,G,T,2]
    float* goals = out + (size_t)Bn * Gn * Tn * 2;                 // [B,G,2]
    float* probs = out + (size_t)Bn * Gn * Tn * 2 + (size_t)Bn * Gn * 2;  // [B,G]

    k_phaseA<<<Bn / 64, 256, 0, stream>>>(eh, lp, gpw1, gpb1, gpw2, gpb2,
                                          prw1, prb1, prw2, prb2, goals, probs);
    k_lstm<<<(Bn * Gn) / 64, 512, 0, stream>>>(eh, ec, lp, wih, whh, bih, bhh,
                                               phw, phb, goals, preds);
}